// Round 6
// baseline (300.151 us; speedup 1.0000x reference)
//
#include <hip/hip_runtime.h>

// Unfold (im2col): x[8,64,224,224] f32, 3x3 kernel, pad=1, stride=1, dil=1
// out[b, c*9 + k, oh*224 + ow] = x[b, c, oh+ki-1, ow+kj-1] (0 outside), k = ki*3+kj
//
// R3 structure, 16-wide per thread: thread owns 16 consecutive cols of one
// image row (224 = 14*16, never crosses rows). Loads 3 rows x (4 aligned
// float4 + 2 edge scalars), composes kj shifts in-register, 36 float4 stores.
// Per wave: 9 write streams x 4KB (vs R3's 9 x 2KB). R2/R4 lessons: L2 merges
// lane-interleaved stores (per-instruction density irrelevant, no nt-stores);
// fewer/longer DRAM streams and less per-byte overhead is the lever.

typedef float v4f __attribute__((ext_vector_type(4)));

constexpr int B = 8, C = 64, H = 224, W = 224;
constexpr int L   = H * W;          // 50176
constexpr int L4  = L / 4;          // 12544 quads per image row-block
constexpr int L16 = L / 16;         // 3136 segments per image
constexpr int WSEG = W / 16;        // 14 segments per row
constexpr int CC = B * C;           // 512
constexpr unsigned TOTALT = (unsigned)CC * (unsigned)L16;  // 1,605,632 = 6272*256

__global__ __launch_bounds__(256) void unfold16w_kernel(const float* __restrict__ x,
                                                        float* __restrict__ out) {
    unsigned t   = blockIdx.x * 256u + threadIdx.x;   // no tail
    unsigned l16 = t % (unsigned)L16;   // const-divisor -> magic mul
    unsigned cc  = t / (unsigned)L16;
    int oh = (int)(l16 / (unsigned)WSEG);             // magic mul by 14
    int ow = (int)(l16 - (unsigned)oh * (unsigned)WSEG) * 16;  // 0..208

    const float* __restrict__ base = x + (size_t)cc * (size_t)L;

    v4f   q[3][4];
    float lft[3], rgt[3];
    #pragma unroll
    for (int ki = 0; ki < 3; ++ki) {
        int ih = oh + ki - 1;
        if (ih >= 0 && ih < H) {
            const float* __restrict__ src = base + ih * W;
            #pragma unroll
            for (int j = 0; j < 4; ++j)
                q[ki][j] = *reinterpret_cast<const v4f*>(src + ow + 4 * j);  // aligned
            lft[ki] = (ow > 0)      ? src[ow - 1]  : 0.f;
            rgt[ki] = (ow < W - 16) ? src[ow + 16] : 0.f;
        } else {
            #pragma unroll
            for (int j = 0; j < 4; ++j) q[ki][j] = (v4f)0.f;
            lft[ki] = 0.f; rgt[ki] = 0.f;
        }
    }

    v4f* __restrict__ o = reinterpret_cast<v4f*>(out);
    // quad index of segment start within image = l16*4
    size_t ob = (size_t)cc * 9u * (size_t)L4 + (size_t)(l16 * 4u);
    #pragma unroll
    for (int ki = 0; ki < 3; ++ki) {
        v4f q0 = q[ki][0], q1 = q[ki][1], q2 = q[ki][2], q3 = q[ki][3];
        size_t r0 = ob + (size_t)(ki * 3 + 0) * (size_t)L4;
        size_t r1 = ob + (size_t)(ki * 3 + 1) * (size_t)L4;
        size_t r2 = ob + (size_t)(ki * 3 + 2) * (size_t)L4;
        // kj = 0: cols ow-1 .. ow+14
        o[r0 + 0] = v4f{ lft[ki], q0[0], q0[1], q0[2] };
        o[r0 + 1] = v4f{ q0[3],   q1[0], q1[1], q1[2] };
        o[r0 + 2] = v4f{ q1[3],   q2[0], q2[1], q2[2] };
        o[r0 + 3] = v4f{ q2[3],   q3[0], q3[1], q3[2] };
        // kj = 1: cols ow .. ow+15
        o[r1 + 0] = q0;
        o[r1 + 1] = q1;
        o[r1 + 2] = q2;
        o[r1 + 3] = q3;
        // kj = 2: cols ow+1 .. ow+16
        o[r2 + 0] = v4f{ q0[1], q0[2], q0[3], q1[0] };
        o[r2 + 1] = v4f{ q1[1], q1[2], q1[3], q2[0] };
        o[r2 + 2] = v4f{ q2[1], q2[2], q2[3], q3[0] };
        o[r2 + 3] = v4f{ q3[1], q3[2], q3[3], rgt[ki] };
    }
}

extern "C" void kernel_launch(void* const* d_in, const int* in_sizes, int n_in,
                              void* d_out, int out_size, void* d_ws, size_t ws_size,
                              hipStream_t stream) {
    const float* x = (const float*)d_in[0];
    float* out = (float*)d_out;
    unsigned blocks = TOTALT / 256u;  // 6,272
    unfold16w_kernel<<<dim3(blocks), dim3(256), 0, stream>>>(x, out);
}

// Round 7
// 171.423 us; speedup vs baseline: 1.7509x; 1.7509x over previous
//
#include <hip/hip_runtime.h>

// Unfold (im2col): x[8,64,224,224] f32, 3x3 kernel, pad=1, stride=1, dil=1
// out[b, c*9 + k, oh*224 + ow] = x[b, c, oh+ki-1, ow+kj-1] (0 outside), k = ki*3+kj
//
// Paired-quad mapping (R4): lane l of wave w owns image-quads w*128+l and
// w*128+64+l => EVERY store instruction is a 1KB-aligned contiguous 1KB burst
// = 8 COMPLETE 128B lines. That makes nontemporal stores safe (R2's nt
// amplification came from partial-line instructions). nt bypasses L2 for the
// 925MB write-once stream, preserving L2 for the 3x-reused input.

typedef float v4f __attribute__((ext_vector_type(4)));

constexpr int B = 8, C = 64, H = 224, W = 224;
constexpr int L  = H * W;          // 50176
constexpr int L4 = L / 4;          // 12544 quads per image; 12544 % 128 == 0
constexpr int W4 = W / 4;          // 56 quads per row
constexpr int CC = B * C;          // 512
constexpr unsigned QTOT   = (unsigned)CC * (unsigned)L4;  // 6,422,528 quads
constexpr unsigned TOTALT = QTOT / 2u;                    // 3,211,264 threads

__global__ __launch_bounds__(256) void unfold_pq_nt_kernel(const float* __restrict__ x,
                                                           float* __restrict__ out) {
    unsigned t    = blockIdx.x * 256u + threadIdx.x;
    unsigned wv   = t >> 6;
    unsigned lane = t & 63u;
    unsigned qA   = wv * 128u + lane;          // wave covers quads [wv*128, wv*128+127]

    unsigned cc   = qA / (unsigned)L4;         // magic-mul; wave never straddles cc
    unsigned remA = qA - cc * (unsigned)L4;

    const float* __restrict__ base = x + (size_t)cc * (size_t)L;

    v4f   q[2][3];
    float lf[2][3], rg[2][3];
    unsigned rem[2] = { remA, remA + 64u };    // remA + 64 < L4 guaranteed

    #pragma unroll
    for (int s = 0; s < 2; ++s) {
        unsigned r  = rem[s];
        int oh  = (int)(r / (unsigned)W4);     // magic-mul
        int col = (int)(r - (unsigned)oh * (unsigned)W4) * 4;   // 0..220, 16B-aligned
        #pragma unroll
        for (int ki = 0; ki < 3; ++ki) {
            int ih = oh + ki - 1;
            if (ih >= 0 && ih < H) {
                const float* __restrict__ src = base + ih * W;
                q[s][ki]  = *reinterpret_cast<const v4f*>(src + col);  // packed across lanes
                lf[s][ki] = (col > 0)     ? src[col - 1] : 0.f;
                rg[s][ki] = (col < W - 4) ? src[col + 4] : 0.f;
            } else {
                q[s][ki] = (v4f)0.f; lf[s][ki] = 0.f; rg[s][ki] = 0.f;
            }
        }
    }

    v4f* __restrict__ o = reinterpret_cast<v4f*>(out);
    size_t cb = (size_t)cc * 9u * (size_t)L4;
    #pragma unroll
    for (int s = 0; s < 2; ++s) {
        size_t ob = cb + (size_t)rem[s];
        #pragma unroll
        for (int ki = 0; ki < 3; ++ki) {
            v4f qq = q[s][ki];
            v4f a = { lf[s][ki], qq[0], qq[1], qq[2] };   // kj = 0
            v4f c = { qq[1], qq[2], qq[3], rg[s][ki] };   // kj = 2
            __builtin_nontemporal_store(a,  o + ob + (size_t)(ki * 3 + 0) * (size_t)L4);
            __builtin_nontemporal_store(qq, o + ob + (size_t)(ki * 3 + 1) * (size_t)L4);
            __builtin_nontemporal_store(c,  o + ob + (size_t)(ki * 3 + 2) * (size_t)L4);
        }
    }
}

extern "C" void kernel_launch(void* const* d_in, const int* in_sizes, int n_in,
                              void* d_out, int out_size, void* d_ws, size_t ws_size,
                              hipStream_t stream) {
    const float* x = (const float*)d_in[0];
    float* out = (float*)d_out;
    unsigned blocks = TOTALT / 256u;  // 12,544
    unfold_pq_nt_kernel<<<dim3(blocks), dim3(256), 0, stream>>>(x, out);
}